// Round 3
// baseline (249.123 us; speedup 1.0000x reference)
//
#include <hip/hip_runtime.h>

#define OUT_DIM 4096
#define DPC     16
#define NCOL    65536    // OUT_DIM * DPC
#define BATCH   512
#define WPB     512      // windows per block
#define SPAN    7681     // 15*(WPB-1) + 16 : input span of one block's windows
#define SPAN_F4 1921     // ceil(SPAN/4)

// Kernel 1: bf[p] = exp((1/16 - duty[p]) * bs), double-prec exp rounded to fp32
__global__ void boost_table_kernel(const float* __restrict__ duty,
                                   const float* __restrict__ bs_ptr,
                                   float* __restrict__ bf) {
    int p = blockIdx.x * blockDim.x + threadIdx.x;
    if (p < NCOL) {
        float t = (0.0625f - duty[p]) * bs_ptr[0];
        bf[p] = (float)exp((double)t);
    }
}

// Kernel 2: block = 512 windows of one batch row.
//  stage boosted span -> LDS (float4 coalesced), thread-per-window argmax from
//  LDS (stride-15 words, conflict-free), coalesced float4 gated epilogue.
__global__ __launch_bounds__(256) void dkw_kernel(const float* __restrict__ x,
                                                  const float* __restrict__ bf,
                                                  float* __restrict__ out) {
    __shared__ float s_boost[SPAN_F4 * 4];   // 7684 floats
    __shared__ int   s_jstar[WPB];

    const int tid = threadIdx.x;
    const int row = blockIdx.x >> 3;          // 8 blocks per row
    const int w0  = (blockIdx.x & 7) * WPB;   // first window of this block
    const int rowbase = row << 16;            // row * 65536 (fits int32)

    // ---- stage boosted = x * bf for the window span ----
    const int in_off = w0 * 15;               // multiple of 7680 -> 16B aligned
    const float4* __restrict__ xg = (const float4*)(x + rowbase + in_off);
    const float4* __restrict__ bg = (const float4*)(bf + in_off);
    float4* __restrict__ sb4 = (float4*)s_boost;
    #pragma unroll
    for (int i = tid; i < SPAN_F4; i += 256) {
        float4 a = xg[i];
        float4 b = bg[i];
        float4 p;
        p.x = a.x * b.x; p.y = a.y * b.y; p.z = a.z * b.z; p.w = a.w * b.w;
        sb4[i] = p;
    }
    __syncthreads();

    // ---- thread-per-window argmax (first-index tie-break, like np.argmax) ----
    #pragma unroll
    for (int r = 0; r < 2; ++r) {
        const int w = tid + r * 256;          // local window id 0..511
        const float* __restrict__ p = s_boost + w * 15;
        float best = p[0];
        int   bj   = 0;
        #pragma unroll
        for (int k = 1; k < DPC; ++k) {
            float v = p[k];
            if (v > best) { best = v; bj = k; }
        }
        s_jstar[w] = bj;
    }
    __syncthreads();

    // ---- gated epilogue: 8192 output cols, float4 in / float4 out ----
    const int out_off = rowbase + (w0 << 4);
    const float4* __restrict__ xo = (const float4*)(x + out_off);
    float4* __restrict__ og = (float4*)(out + out_off);
    #pragma unroll
    for (int i = tid; i < (WPB * DPC) / 4; i += 256) {   // 2048 float4
        float4 v = xo[i];
        const int w  = i >> 2;                 // window within block
        const int jm = s_jstar[w];
        const int j  = (i & 3) << 2;           // first j of this float4
        float4 o;
        o.x = (j     == jm) ? v.x : 0.0f;
        o.y = (j + 1 == jm) ? v.y : 0.0f;
        o.z = (j + 2 == jm) ? v.z : 0.0f;
        o.w = (j + 3 == jm) ? v.w : 0.0f;
        og[i] = o;
    }
}

extern "C" void kernel_launch(void* const* d_in, const int* in_sizes, int n_in,
                              void* d_out, int out_size, void* d_ws, size_t ws_size,
                              hipStream_t stream) {
    const float* x    = (const float*)d_in[0];
    const float* duty = (const float*)d_in[1];
    const float* bs   = (const float*)d_in[2];
    float* out = (float*)d_out;
    float* bf  = (float*)d_ws;   // 65536 floats = 256 KiB scratch

    hipLaunchKernelGGL(boost_table_kernel, dim3(NCOL / 256), dim3(256), 0, stream,
                       duty, bs, bf);
    hipLaunchKernelGGL(dkw_kernel, dim3(BATCH * 8), dim3(256), 0, stream,
                       x, bf, out);
}

// Round 4
// 240.015 us; speedup vs baseline: 1.0379x; 1.0379x over previous
//
#include <hip/hip_runtime.h>

#define OUT_DIM 4096
#define DPC     16
#define NCOL    65536    // OUT_DIM * DPC
#define BATCH   512
#define WPB     256      // windows per block
#define BPR     16       // blocks per row
#define SPAN_F4 1024     // f4 loads per block (4096 floats >= 15*255+16, in-row safe)

// Kernel 1: bf[p] = exp((1/16 - duty[p]) * bs), double-prec exp rounded to fp32
__global__ void boost_table_kernel(const float* __restrict__ duty,
                                   const float* __restrict__ bs_ptr,
                                   float* __restrict__ bf) {
    int p = blockIdx.x * blockDim.x + threadIdx.x;
    if (p < NCOL) {
        float t = (0.0625f - duty[p]) * bs_ptr[0];
        bf[p] = (float)exp((double)t);
    }
}

// Kernel 2: block = 256 windows of one batch row, 8 blocks/CU resident.
//  P1: stage boosted span -> LDS (uniform 4 float4/thread, fully unrolled)
//  P2: thread-per-window argmax from LDS (stride-15 words: 2-way = free),
//      then ONE scalar global load of the winner value (L2/L3-hot)
//  P3: pure-store coalesced float4 epilogue (no global reads)
__global__ __launch_bounds__(256, 8) void dkw_kernel(const float* __restrict__ x,
                                                     const float* __restrict__ bf,
                                                     float* __restrict__ out) {
    __shared__ float s_boost[SPAN_F4 * 4];   // 16 KiB
    __shared__ int   s_jstar[WPB];           // 1 KiB
    __shared__ float s_wval[WPB];            // 1 KiB

    const int tid = threadIdx.x;
    const int row = blockIdx.x >> 4;          // 16 blocks per row
    const int w0  = (blockIdx.x & 15) * WPB;  // first window of this block
    const int rowbase = row << 16;            // row * 65536

    // ---- P1: stage boosted = x * bf (15*w0 is 16B-aligned; overshoot stays in-row) ----
    const int in_off = w0 * 15;
    const float4* __restrict__ xg = (const float4*)(x + rowbase + in_off);
    const float4* __restrict__ bg = (const float4*)(bf + in_off);
    float4* __restrict__ sb4 = (float4*)s_boost;
    #pragma unroll
    for (int r = 0; r < 4; ++r) {
        const int i = tid + r * 256;
        float4 a = xg[i];
        float4 b = bg[i];
        float4 p;
        p.x = a.x * b.x; p.y = a.y * b.y; p.z = a.z * b.z; p.w = a.w * b.w;
        sb4[i] = p;
    }
    __syncthreads();

    // ---- P2: argmax of window tid (first-index tie-break = np.argmax) ----
    {
        const float* __restrict__ p = s_boost + tid * 15;
        float best = p[0];
        int   bj   = 0;
        #pragma unroll
        for (int k = 1; k < DPC; ++k) {
            float v = p[k];
            if (v > best) { best = v; bj = k; }
        }
        s_jstar[tid] = bj;
        // winner value: single scalar load, L2/L3-hot (x span just streamed)
        s_wval[tid] = x[rowbase + ((w0 + tid) << 4) + bj];
    }
    __syncthreads();

    // ---- P3: pure-store epilogue: 1024 float4, perfectly coalesced ----
    float4* __restrict__ og = (float4*)(out + rowbase + (w0 << 4));
    #pragma unroll
    for (int r = 0; r < 4; ++r) {
        const int i  = tid + r * 256;
        const int w  = i >> 2;                 // window within block
        const int jm = s_jstar[w];
        const float wv = s_wval[w];
        const int j  = (i & 3) << 2;           // first j of this float4
        float4 o;
        o.x = (j     == jm) ? wv : 0.0f;
        o.y = (j + 1 == jm) ? wv : 0.0f;
        o.z = (j + 2 == jm) ? wv : 0.0f;
        o.w = (j + 3 == jm) ? wv : 0.0f;
        og[i] = o;
    }
}

extern "C" void kernel_launch(void* const* d_in, const int* in_sizes, int n_in,
                              void* d_out, int out_size, void* d_ws, size_t ws_size,
                              hipStream_t stream) {
    const float* x    = (const float*)d_in[0];
    const float* duty = (const float*)d_in[1];
    const float* bs   = (const float*)d_in[2];
    float* out = (float*)d_out;
    float* bf  = (float*)d_ws;   // 65536 floats = 256 KiB scratch

    hipLaunchKernelGGL(boost_table_kernel, dim3(NCOL / 256), dim3(256), 0, stream,
                       duty, bs, bf);
    hipLaunchKernelGGL(dkw_kernel, dim3(BATCH * BPR), dim3(256), 0, stream,
                       x, bf, out);
}

// Round 5
// 237.213 us; speedup vs baseline: 1.0502x; 1.0118x over previous
//
#include <hip/hip_runtime.h>

#define OUT_DIM 4096
#define DPC     16
#define NCOL    65536    // OUT_DIM * DPC
#define BATCH   512
#define NWAVE   32768    // total 64-window chunks (2M windows / 64)

// Kernel 1: bf[p] = exp((1/16 - duty[p]) * bs), double-prec exp rounded to fp32
__global__ void boost_table_kernel(const float* __restrict__ duty,
                                   const float* __restrict__ bs_ptr,
                                   float* __restrict__ bf) {
    int p = blockIdx.x * blockDim.x + threadIdx.x;
    if (p < NCOL) {
        float t = (0.0625f - duty[p]) * bs_ptr[0];
        bf[p] = (float)exp((double)t);
    }
}

// Kernel 2: WAVE-INDEPENDENT streaming. Each wave64 owns 64 windows and a
// private LDS region; no __syncthreads anywhere (waves never exchange data),
// so waves free-run and reads/writes from different waves stay interleaved.
// Wave-synchronous LDS: DS pipe is in-order per wave; __threadfence_block()
// (s_waitcnt only, no s_barrier) stops compiler reordering.
__global__ __launch_bounds__(256, 8) void dkw_kernel(const float* __restrict__ x,
                                                     const float* __restrict__ bf,
                                                     float* __restrict__ out) {
    __shared__ float sb[4][1024];   // boosted span per wave, 16 KiB
    __shared__ int   sj[4][64];     // winner j per window, 1 KiB
    __shared__ float sv[4][64];     // winner value per window, 1 KiB

    const int lane = threadIdx.x & 63;
    const int wv   = threadIdx.x >> 6;                 // wave in block
    const int gw   = blockIdx.x * 4 + wv;              // global wave id
    const int row  = gw >> 6;                          // 64 waves per row
    const int wc   = gw & 63;                          // chunk within row
    const int rowbase = row << 16;                     // row * 65536

    // ---- P1: stage boosted = x*bf for span [960*wc, 960*wc+1024) of row ----
    const int in_off = wc * 960;                       // 16B-aligned (/4=240*wc)
    const float4* __restrict__ xg = (const float4*)(x + rowbase + in_off);
    const float4* __restrict__ bg = (const float4*)(bf + in_off);
    float4* __restrict__ sb4 = (float4*)sb[wv];
    #pragma unroll
    for (int r = 0; r < 4; ++r) {
        const int i = lane + 64 * r;                   // 256 f4 = 1024 floats
        float4 a = xg[i];
        float4 b = bg[i];
        float4 p;
        p.x = a.x * b.x; p.y = a.y * b.y; p.z = a.z * b.z; p.w = a.w * b.w;
        sb4[i] = p;
    }
    __threadfence_block();   // order ds_write -> ds_read within wave, no barrier

    // ---- P2: lane = window wc*64+lane; argmax over LDS stride-15 ----
    {
        const float* __restrict__ p = sb[wv] + lane * 15;   // 2-way bank = free
        float best = p[0];
        int   bj   = 0;
        #pragma unroll
        for (int k = 1; k < DPC; ++k) {
            float v = p[k];
            if (v > best) { best = v; bj = k; }
        }
        sj[wv][lane] = bj;
        // winner value x[16*w + bj] (output-stride chunk), scalar, L2/L3-hot
        sv[wv][lane] = x[rowbase + ((wc * 64 + lane) << 4) + bj];
    }
    __threadfence_block();

    // ---- P3: coalesced pure-store epilogue: 256 f4 = 4 KiB output span ----
    float4* __restrict__ og = (float4*)(out + rowbase + (wc << 10));
    #pragma unroll
    for (int r = 0; r < 4; ++r) {
        const int i  = lane + 64 * r;
        const int w  = i >> 2;                // window within chunk (broadcast x4)
        const int jm = sj[wv][w];
        const float val = sv[wv][w];
        const int j0 = (i & 3) << 2;
        float4 o;
        o.x = (j0     == jm) ? val : 0.0f;
        o.y = (j0 + 1 == jm) ? val : 0.0f;
        o.z = (j0 + 2 == jm) ? val : 0.0f;
        o.w = (j0 + 3 == jm) ? val : 0.0f;
        og[i] = o;
    }
}

extern "C" void kernel_launch(void* const* d_in, const int* in_sizes, int n_in,
                              void* d_out, int out_size, void* d_ws, size_t ws_size,
                              hipStream_t stream) {
    const float* x    = (const float*)d_in[0];
    const float* duty = (const float*)d_in[1];
    const float* bs   = (const float*)d_in[2];
    float* out = (float*)d_out;
    float* bf  = (float*)d_ws;   // 65536 floats = 256 KiB scratch

    hipLaunchKernelGGL(boost_table_kernel, dim3(NCOL / 256), dim3(256), 0, stream,
                       duty, bs, bf);
    hipLaunchKernelGGL(dkw_kernel, dim3(NWAVE / 4), dim3(256), 0, stream,
                       x, bf, out);
}